// Round 1
// baseline (69.361 us; speedup 1.0000x reference)
//
#include <hip/hip_runtime.h>
#include <math.h>

#define TAGS   20
#define TSTART (TAGS - 2)
#define TSTOP  (TAGS - 1)

#if __has_builtin(__builtin_amdgcn_exp2f)
__device__ __forceinline__ float fexp2(float x) { return __builtin_amdgcn_exp2f(x); }
#else
__device__ __forceinline__ float fexp2(float x) { return exp2f(x); }
#endif
#if __has_builtin(__builtin_amdgcn_logf)
__device__ __forceinline__ float flog2(float x) { return __builtin_amdgcn_logf(x); }
#else
__device__ __forceinline__ float flog2(float x) { return log2f(x); }
#endif

// broadcast lane `srclane`'s value to all lanes (lands in SGPR -> legal FMA scalar operand)
__device__ __forceinline__ float bcast(float v, int srclane) {
    return __int_as_float(__builtin_amdgcn_readlane(__float_as_int(v), srclane));
}

// One wave (64 threads) per batch element. Lanes 0..TAGS-1 own tag columns.
// Recurrence in base-2 log domain; broadcast ew = 2^w so the inner logsumexp
// is a pure 20-FMA dot with precomputed ET = 2^(T*log2e). Running offset M2
// (double) absorbs magnitude each step via b0 = w[0].
__global__ __launch_bounds__(64)
void crf_fwd_kernel(const float* __restrict__ feats,
                    const float* __restrict__ Tm,
                    const int*   __restrict__ tags,
                    const int*   __restrict__ lengths,
                    double*      __restrict__ partial,
                    int B, int L)
{
    constexpr float  LOG2E = 1.4426950408889634f;
    constexpr double LN2d  = 0.69314718055994530942;

    __shared__ float lf[512 * TAGS];   // 40 KB: feats[b] staged in LDS

    const int b    = blockIdx.x;
    if (b >= B) return;
    const int lane = threadIdx.x;
    const int j    = (lane < TAGS) ? lane : 0;

    const float* fb = feats + (size_t)b * L * TAGS;
    const int*   tg = tags  + (size_t)b * L;
    const int    len = lengths[b];

    // ---- bulk-stage feats[b] (L*TAGS floats, multiple of 4) into LDS ----
    const int nv4 = (L * TAGS) >> 2;
    #pragma unroll 8
    for (int it = lane; it < nv4; it += 64) {
        float4 v = reinterpret_cast<const float4*>(fb)[it];
        reinterpret_cast<float4*>(lf)[it] = v;
    }
    __syncthreads();

    // ---- per-lane T column: ET[i] = 2^(T[i][j]*log2e) ----
    float ET[TAGS];
    #pragma unroll
    for (int i = 0; i < TAGS; ++i)
        ET[i] = fexp2(Tm[i * TAGS + j] * LOG2E);
    const float Ts2 = Tm[j * TAGS + TSTOP] * LOG2E;   // for the final LSE

    // ---- init: part0 = feats[b,0,:] + T[START,:]  (base-2) ----
    float  p0  = (lf[j] + Tm[TSTART * TAGS + j]) * LOG2E;
    float  p00 = bcast(p0, 0);
    float  w   = p0 - p00;          // own normalized log2-part (lane j)
    double M2  = (double)p00;       // uniform offset (log2 domain)
    float  ew  = fexp2(w);
    float  ewa[TAGS];
    #pragma unroll
    for (int i = 0; i < TAGS; ++i) ewa[i] = bcast(ew, i);

    // ---- recurrence over time steps 1..len-1 ----
    float fA = lf[((1 < L) ? 1 : 0) * TAGS + j];
    float fB = lf[((2 < L) ? 2 : 0) * TAGS + j];
    for (int l = 1; l < len; ++l) {
        const int lp = (l + 2 < L) ? (l + 2) : (L - 1);
        float fC = lf[lp * TAGS + j];               // LDS prefetch, 2 deep

        float b0 = flog2(ewa[0]);                   // ~= w[0], exact invariant either way
        float s0 = 0.f, s1 = 0.f, s2 = 0.f, s3 = 0.f;
        #pragma unroll
        for (int i = 0; i < TAGS; i += 4) {
            s0 = fmaf(ET[i + 0], ewa[i + 0], s0);
            s1 = fmaf(ET[i + 1], ewa[i + 1], s1);
            s2 = fmaf(ET[i + 2], ewa[i + 2], s2);
            s3 = fmaf(ET[i + 3], ewa[i + 3], s3);
        }
        float s   = (s0 + s1) + (s2 + s3);
        float cur = fmaf(fA, LOG2E, flog2(s) - b0); // new own log2-part (normalized)
        M2 += (double)b0;
        w  = cur;
        ew = fexp2(cur);
        #pragma unroll
        for (int i = 0; i < TAGS; ++i) ewa[i] = bcast(ew, i);
        fA = fB; fB = fC;
    }

    // ---- final: forward_b = ln( sum_i exp(part_i + T[i,STOP]) ) ----
    float v = (lane < TAGS) ? (w + Ts2) : -INFINITY;
    float m = v;
    #pragma unroll
    for (int off = 32; off; off >>= 1)
        m = fmaxf(m, __shfl_xor(m, off));
    float e = (lane < TAGS) ? fexp2(v - m) : 0.f;
    #pragma unroll
    for (int off = 32; off; off >>= 1)
        e += __shfl_xor(e, off);
    double fwd = (M2 + (double)m + (double)flog2(e)) * LN2d;

    // ---- gold path score (all 64 lanes, strided over l) ----
    float g = 0.f;
    for (int l = lane; l < len; l += 64) {
        int t  = tg[l];
        int pv = (l == 0) ? TSTART : tg[l - 1];
        g += lf[l * TAGS + t] + Tm[pv * TAGS + t];
    }
    #pragma unroll
    for (int off = 32; off; off >>= 1)
        g += __shfl_xor(g, off);

    if (lane == 0) {
        double gold = (double)g + (double)Tm[tg[len - 1] * TAGS + TSTOP];
        partial[b] = fwd - gold;
    }
}

// Deterministic tree reduce of per-batch partials -> scalar output.
__global__ __launch_bounds__(256)
void crf_reduce_kernel(const double* __restrict__ partial, float* __restrict__ out, int B)
{
    __shared__ double sh[256];
    const int t = threadIdx.x;
    double acc = 0.0;
    for (int i = t; i < B; i += 256) acc += partial[i];
    sh[t] = acc;
    __syncthreads();
    for (int s = 128; s; s >>= 1) {
        if (t < s) sh[t] += sh[t + s];
        __syncthreads();
    }
    if (t == 0) out[0] = (float)sh[0];
}

extern "C" void kernel_launch(void* const* d_in, const int* in_sizes, int n_in,
                              void* d_out, int out_size, void* d_ws, size_t ws_size,
                              hipStream_t stream)
{
    const float* feats   = (const float*)d_in[0];
    const float* Tm      = (const float*)d_in[1];
    const int*   tags    = (const int*)d_in[2];
    const int*   lengths = (const int*)d_in[3];

    const int B = in_sizes[3];
    const int L = in_sizes[2] / B;

    double* partial = (double*)d_ws;

    crf_fwd_kernel<<<B, 64, 0, stream>>>(feats, Tm, tags, lengths, partial, B, L);
    crf_reduce_kernel<<<1, 256, 0, stream>>>(partial, (float*)d_out, B);
}

// Round 2
// 65.375 us; speedup vs baseline: 1.0610x; 1.0610x over previous
//
#include <hip/hip_runtime.h>
#include <math.h>

#define TAGS   20
#define TSTART (TAGS - 2)
#define TSTOP  (TAGS - 1)

#if __has_builtin(__builtin_amdgcn_exp2f)
__device__ __forceinline__ float fexp2(float x) { return __builtin_amdgcn_exp2f(x); }
#else
__device__ __forceinline__ float fexp2(float x) { return exp2f(x); }
#endif
#if __has_builtin(__builtin_amdgcn_logf)
__device__ __forceinline__ float flog2(float x) { return __builtin_amdgcn_logf(x); }
#else
__device__ __forceinline__ float flog2(float x) { return log2f(x); }
#endif
__device__ __forceinline__ float frcp(float x) {
#if __has_builtin(__builtin_amdgcn_rcpf)
    return __builtin_amdgcn_rcpf(x);
#else
    return 1.0f / x;
#endif
}

// broadcast lane `srclane`'s value to all lanes (uniform -> SGPR)
__device__ __forceinline__ float bcast(float v, int srclane) {
    return __int_as_float(__builtin_amdgcn_readlane(__float_as_int(v), srclane));
}

// One wave per batch element; lanes 0..19 own tag columns.
// Linear-domain forward recurrence: P' = (ET^T P) .* EF, with EF = 2^(feat*log2e)
// precomputed in LDS. Renorm every 4 steps by folding rcp(P0) into the next
// step's EF multiply (off the critical path); M2 (float, log2 domain) tracks
// the running offset, accumulated only when the scale is actually applied.
__global__ __launch_bounds__(64)
void crf_fwd_kernel(const float* __restrict__ feats,
                    const float* __restrict__ Tm,
                    const int*   __restrict__ tags,
                    const int*   __restrict__ lengths,
                    double*      __restrict__ partial,
                    int B, int L)
{
    constexpr float  LOG2E = 1.4426950408889634f;
    constexpr float  LN2f  = 0.6931471805599453f;
    constexpr double LN2d  = 0.69314718055994530942;

    __shared__ float le[512 * TAGS];   // 40 KB: 2^(feats*log2e)

    const int b    = blockIdx.x;
    const int lane = threadIdx.x;
    const int j    = (lane < TAGS) ? lane : 0;

    const float* fb  = feats + (size_t)b * L * TAGS;
    const int*   tg  = tags  + (size_t)b * L;
    const int    len = lengths[b];

    // ---- stage EF = 2^(feat*log2e) into LDS (L*TAGS multiple of 4) ----
    const int nv4 = (L * TAGS) >> 2;
    for (int it = lane; it < nv4; it += 64) {
        float4 v = reinterpret_cast<const float4*>(fb)[it];
        float4 e;
        e.x = fexp2(v.x * LOG2E); e.y = fexp2(v.y * LOG2E);
        e.z = fexp2(v.z * LOG2E); e.w = fexp2(v.w * LOG2E);
        reinterpret_cast<float4*>(le)[it] = e;
    }
    __syncthreads();

    // ---- per-lane transition column: ET[i] = 2^(T[i][j]*log2e) ----
    float ET[TAGS];
    #pragma unroll
    for (int i = 0; i < TAGS; ++i)
        ET[i] = fexp2(Tm[i * TAGS + j] * LOG2E);

    // ---- init: part0 = feats[b,0,:] + T[START,:]  (log2 domain) ----
    float w0   = flog2(le[j]) + Tm[TSTART * TAGS + j] * LOG2E;
    float base = bcast(w0, 0);
    float P    = fexp2(w0 - base);   // lane0 == 1 exactly
    float M2   = base;
    float Pa[TAGS];
    #pragma unroll
    for (int i = 0; i < TAGS; ++i) Pa[i] = bcast(P, i);

    const float* leb = le + j;

    auto STEP = [&](int l, float efv, float rsv, bool scaled) {
        float s0 = 0.f, s1 = 0.f, s2 = 0.f, s3 = 0.f;
        #pragma unroll
        for (int i = 0; i < TAGS; i += 4) {
            s0 = fmaf(ET[i + 0], Pa[i + 0], s0);
            s1 = fmaf(ET[i + 1], Pa[i + 1], s1);
            s2 = fmaf(ET[i + 2], Pa[i + 2], s2);
            s3 = fmaf(ET[i + 3], Pa[i + 3], s3);
        }
        float s   = (s0 + s1) + (s2 + s3);
        float cur = s * efv;
        float pn  = (l < len) ? cur : P;     // mask: frozen past len
        P = scaled ? pn * rsv : pn;          // renorm applies to both branches
        #pragma unroll
        for (int i = 0; i < TAGS; ++i) Pa[i] = bcast(P, i);
    };

    // EF quad double-buffer
    float efb[4];
    #pragma unroll
    for (int k = 0; k < 4; ++k) {
        int ln = 1 + k; ln = (ln < L) ? ln : (L - 1);
        efb[k] = leb[ln * TAGS];
    }

    float rs  = 1.0f;   // pending renorm scale (applied at next quad's 1st step)
    float lg0 = 0.0f;   // pending log2(p0), added to M2 only when rs is applied
    int l0 = 1;
    for (; l0 + 3 < L; l0 += 4) {
        if (l0 >= len) break;              // dead forever; pending stays unapplied
        float efn[4];
        #pragma unroll
        for (int k = 0; k < 4; ++k) {
            int ln = l0 + 4 + k; ln = (ln < L) ? ln : (L - 1);
            efn[k] = leb[ln * TAGS];
        }
        M2 += lg0;
        STEP(l0 + 0, efb[0], rs, true);
        STEP(l0 + 1, efb[1], 1.f, false);
        STEP(l0 + 2, efb[2], 1.f, false);
        STEP(l0 + 3, efb[3], 1.f, false);
        float p0 = Pa[0];
        rs  = frcp(p0);
        lg0 = flog2(p0);
        #pragma unroll
        for (int k = 0; k < 4; ++k) efb[k] = efn[k];
    }
    // tail (up to 3 steps), static indices only
    if (l0 < len) {
        int rem = L - l0;
        M2 += lg0;
        if (rem > 0) STEP(l0 + 0, efb[0], rs, true);
        if (rem > 1) STEP(l0 + 1, efb[1], 1.f, false);
        if (rem > 2) STEP(l0 + 2, efb[2], 1.f, false);
        if (rem > 3) STEP(l0 + 3, efb[3], 1.f, false);
    }

    // ---- final: fwd = M2*ln2 + mc + ln( sum_j P_j * e^(c_j - mc) ), c = T[:,STOP]
    float cstop = Tm[j * TAGS + TSTOP];
    float mc = (lane < TAGS) ? cstop : -INFINITY;
    #pragma unroll
    for (int off = 32; off; off >>= 1)
        mc = fmaxf(mc, __shfl_xor(mc, off));
    float t = (lane < TAGS) ? P * fexp2((cstop - mc) * LOG2E) : 0.f;
    #pragma unroll
    for (int off = 32; off; off >>= 1)
        t += __shfl_xor(t, off);
    double fwd = ((double)M2 + (double)flog2(t)) * LN2d + (double)mc;

    // ---- gold path score (feats recovered from le; roundtrip err ~1e-5) ----
    float g = 0.f;
    for (int l = lane; l < len; l += 64) {
        int tt = tg[l];
        int pv = (l == 0) ? TSTART : tg[l - 1];
        g += flog2(le[l * TAGS + tt]) * LN2f + Tm[pv * TAGS + tt];
    }
    #pragma unroll
    for (int off = 32; off; off >>= 1)
        g += __shfl_xor(g, off);

    if (lane == 0) {
        double gold = (double)g + (double)Tm[tg[len - 1] * TAGS + TSTOP];
        partial[b] = fwd - gold;
    }
}

// Deterministic tree reduce of per-batch partials -> scalar output.
__global__ __launch_bounds__(256)
void crf_reduce_kernel(const double* __restrict__ partial, float* __restrict__ out, int B)
{
    __shared__ double sh[256];
    const int t = threadIdx.x;
    double acc = 0.0;
    for (int i = t; i < B; i += 256) acc += partial[i];
    sh[t] = acc;
    __syncthreads();
    for (int s = 128; s; s >>= 1) {
        if (t < s) sh[t] += sh[t + s];
        __syncthreads();
    }
    if (t == 0) out[0] = (float)sh[0];
}

extern "C" void kernel_launch(void* const* d_in, const int* in_sizes, int n_in,
                              void* d_out, int out_size, void* d_ws, size_t ws_size,
                              hipStream_t stream)
{
    const float* feats   = (const float*)d_in[0];
    const float* Tm      = (const float*)d_in[1];
    const int*   tags    = (const int*)d_in[2];
    const int*   lengths = (const int*)d_in[3];

    const int B = in_sizes[3];
    const int L = in_sizes[2] / B;

    double* partial = (double*)d_ws;

    crf_fwd_kernel<<<B, 64, 0, stream>>>(feats, Tm, tags, lengths, partial, B, L);
    crf_reduce_kernel<<<1, 256, 0, stream>>>(partial, (float*)d_out, B);
}

// Round 4
// 39.510 us; speedup vs baseline: 1.7555x; 1.6546x over previous
//
#include <hip/hip_runtime.h>
#include <hip/hip_bf16.h>
#include <math.h>

#define TAGS   20
#define TSTART (TAGS - 2)
#define TSTOP  (TAGS - 1)

constexpr float  LOG2E = 1.4426950408889634f;
constexpr float  LN2f  = 0.6931471805599453f;
constexpr double LN2d  = 0.69314718055994530942;

typedef __attribute__((ext_vector_type(8))) short short8;
typedef __attribute__((ext_vector_type(4))) float f32x4;
union U4 { unsigned int u[4]; short8 v; };

__device__ __forceinline__ unsigned int pk2(float lo, float hi) {
    float2 f2; f2.x = lo; f2.y = hi;
    __hip_bfloat162 h = __float22bfloat162_rn(f2);
    return *reinterpret_cast<unsigned int*>(&h);
}
// k-slot -> state-row permutation: split-half layout of gfx950 16x16x32
// (elements 0..3 -> k = 4g+e, elements 4..7 -> k = 16+4g+(e-4)); applied
// consistently to A and B, and chosen so C/D per-lane rows == B per-lane k-slots.
__device__ __forceinline__ int rho(int k) {
    int g = k >> 3, i = k & 7;
    return (i < 4) ? (4 * g + i) : (16 + 4 * g + (i - 4));
}
__device__ __forceinline__ float fexp2(float x) { return exp2f(x); }
__device__ __forceinline__ float flog2(float x) { return log2f(x); }
__device__ __forceinline__ float frcp(float x) { return __builtin_amdgcn_rcpf(x); }
__device__ __forceinline__ float bcast(float v, int srclane) {
    return __int_as_float(__builtin_amdgcn_readlane(__float_as_int(v), srclane));
}

// ============================ PHASE 1 =====================================
// wid = b*8 + c. One wave computes the 32x32 (padded) linear-domain product
// G_c = M_lo ... M_hi for its 64-step chunk via 4x mfma_f32_16x16x32_bf16
// per step, iterating l descending with R <- M_l * R. The accumulator feeds
// the next step's B operand directly (rho trick), zero cross-lane ops.
__global__ __launch_bounds__(64)
void crf_chunk_kernel(const float* __restrict__ feats,
                      const float* __restrict__ Tm,
                      const int*   __restrict__ lengths,
                      float*       __restrict__ Gout,
                      int*         __restrict__ Eout,
                      int L)
{
    __shared__ float ef[64 * 32];                 // 8 KB: 2^(feat*log2e), pad cols = 0
    const int wid  = blockIdx.x;
    const int b    = wid >> 3, c = wid & 7;
    const int lane = threadIdx.x;
    const int G    = lane >> 4, col = lane & 15;

    // ---- stage ef for this chunk (64 x 20 real, 12 pad cols) ----
    const float* fc = feats + ((size_t)b * L + (size_t)c * 64) * TAGS;
    #pragma unroll
    for (int q = 0; q < 5; ++q) {
        int it = lane + q * 64;                   // 320 float4 total
        float4 v = reinterpret_cast<const float4*>(fc)[it];
        float vv[4] = {v.x, v.y, v.z, v.w};
        #pragma unroll
        for (int u = 0; u < 4; ++u) {
            int f = it * 4 + u;
            int t = f / TAGS, tag = f - t * TAGS;
            ef[t * 32 + tag] = fexp2(vv[u] * LOG2E);
        }
    }
    for (int q = lane; q < 64 * 12; q += 64) {
        int t = q / 12;
        ef[t * 32 + 20 + (q - t * 12)] = 0.f;
    }
    __syncthreads();

    // ---- A fragments: A_x[m][k] = 2^(T[16x+m][rho(k)]*log2e), bf16, pad=0 ----
    U4 A0, A1;
    #pragma unroll
    for (int t = 0; t < 4; ++t) {
        int k0 = 8 * G + 2 * t;
        int r0 = rho(k0), r1 = rho(k0 + 1);
        int m1 = 16 + col;                        // m0 = col (<20 always)
        float a00 = (r0 < TAGS) ? fexp2(Tm[col * TAGS + r0] * LOG2E) : 0.f;
        float a01 = (r1 < TAGS) ? fexp2(Tm[col * TAGS + r1] * LOG2E) : 0.f;
        float a10 = (m1 < TAGS && r0 < TAGS) ? fexp2(Tm[m1 * TAGS + r0] * LOG2E) : 0.f;
        float a11 = (m1 < TAGS && r1 < TAGS) ? fexp2(Tm[m1 * TAGS + r1] * LOG2E) : 0.f;
        A0.u[t] = pk2(a00, a01);
        A1.u[t] = pk2(a10, a11);
    }

    const int len = lengths[b];
    const int lo  = (c == 0) ? 1 : c * 64;
    const int hiE = min(c * 64 + 63, len - 1);

    // ---- R = I (pad diag harmless: pad rows/cols die after one multiply) ----
    f32x4 C00, C01, C10, C11;
    #pragma unroll
    for (int j = 0; j < 4; ++j) {
        float d = (4 * G + j == col) ? 1.f : 0.f;
        C00[j] = d; C11[j] = d; C01[j] = 0.f; C10[j] = 0.f;
    }
    int Eacc = 0;

    for (int l = hiE; l >= lo; --l) {
        const int t = l - c * 64;
        float4 e0 = *reinterpret_cast<const float4*>(&ef[t * 32 + 4 * G]);        // rows 4G..
        float4 e1 = *reinterpret_cast<const float4*>(&ef[t * 32 + 16 + 4 * G]);   // rows 16+4G..
        U4 B0, B1;
        B0.u[0] = pk2(C00[0] * e0.x, C00[1] * e0.y);
        B0.u[1] = pk2(C00[2] * e0.z, C00[3] * e0.w);
        B0.u[2] = pk2(C10[0] * e1.x, C10[1] * e1.y);
        B0.u[3] = pk2(C10[2] * e1.z, C10[3] * e1.w);
        B1.u[0] = pk2(C01[0] * e0.x, C01[1] * e0.y);
        B1.u[1] = pk2(C01[2] * e0.z, C01[3] * e0.w);
        B1.u[2] = pk2(C11[0] * e1.x, C11[1] * e1.y);
        B1.u[3] = pk2(C11[2] * e1.z, C11[3] * e1.w);
        f32x4 z = {0.f, 0.f, 0.f, 0.f};
        C00 = __builtin_amdgcn_mfma_f32_16x16x32_bf16(A0.v, B0.v, z, 0, 0, 0);
        C01 = __builtin_amdgcn_mfma_f32_16x16x32_bf16(A0.v, B1.v, z, 0, 0, 0);
        C10 = __builtin_amdgcn_mfma_f32_16x16x32_bf16(A1.v, B0.v, z, 0, 0, 0);
        C11 = __builtin_amdgcn_mfma_f32_16x16x32_bf16(A1.v, B1.v, z, 0, 0, 0);
        if ((l & 3) == 0) {                        // exponent-strip renorm
            float pr = C00[0] + C00[1] + C00[2] + C00[3] + C10[0] + C10[1] + C10[2] + C10[3];
            int pb = __builtin_amdgcn_readfirstlane(__float_as_int(pr)); // col0 sample, lane 0
            int ex = ((pb >> 23) & 0xFF) - 127;
            float s = __uint_as_float((unsigned)(127 - ex) << 23);       // 2^-ex
            #pragma unroll
            for (int j = 0; j < 4; ++j) { C00[j] *= s; C01[j] *= s; C10[j] *= s; C11[j] *= s; }
            Eacc += ex;
        }
    }

    float4* go = reinterpret_cast<float4*>(Gout + (size_t)wid * 1024);
    go[0 * 64 + lane] = make_float4(C00[0], C00[1], C00[2], C00[3]);  // blk 2x+y = 0
    go[1 * 64 + lane] = make_float4(C01[0], C01[1], C01[2], C01[3]);  // 1
    go[2 * 64 + lane] = make_float4(C10[0], C10[1], C10[2], C10[3]);  // 2
    go[3 * 64 + lane] = make_float4(C11[0], C11[1], C11[2], C11[3]);  // 3
    if (lane == 0) Eout[wid] = Eacc;
}

// ============================ PHASE 2 =====================================
// One wave per batch: v^T <- p0^T, then v^T <- v^T * G_c for c=0..7, final
// LSE with T[:,STOP] (max-subtracted: the STOP column is -10000 everywhere!),
// gold path score.
__global__ __launch_bounds__(64)
void crf_combine_kernel(const float* __restrict__ feats,
                        const float* __restrict__ Tm,
                        const int*   __restrict__ tags,
                        const int*   __restrict__ lengths,
                        const float* __restrict__ Gmat,
                        const int*   __restrict__ Emat,
                        double*      __restrict__ partial,
                        int L)
{
    __shared__ float sv[32];
    const int b    = blockIdx.x;
    const int lane = threadIdx.x;
    const int n    = lane & 31;                 // lanes 32-63 duplicate (no divergence)
    const int len  = lengths[b];

    float p = (n < TAGS) ? (feats[(size_t)b * L * TAGS + n] + Tm[TSTART * TAGS + n]) * LOG2E
                         : -1e30f;
    float mx = p;
    #pragma unroll
    for (int off = 32; off; off >>= 1) mx = fmaxf(mx, __shfl_xor(mx, off));
    float v = (n < TAGS) ? fexp2(p - mx) : 0.f;
    double Dacc = (double)mx;                   // log2-domain offset

    for (int c = 0; c < 8; ++c) {
        int lo = (c == 0) ? 1 : c * 64;
        if (lo > len - 1) break;                // this & later chunks are identity
        if (lane < 32) sv[lane] = v;            // same-wave DS ordering
        const float* Gc = Gmat + (size_t)(b * 8 + c) * 1024;
        float vn = 0.f;
        #pragma unroll
        for (int r = 0; r < 32; ++r) {          // vn = sum_r v[r] * G[r][n]
            int blk  = 2 * (r >> 4) + (n >> 4);
            int lsrc = 16 * ((r & 15) >> 2) + (n & 15);
            float g  = Gc[blk * 256 + lsrc * 4 + (r & 3)];
            vn = fmaf(sv[r], g, vn);
        }
        float m2 = vn;
        #pragma unroll
        for (int off = 32; off; off >>= 1) m2 = fmaxf(m2, __shfl_xor(m2, off));
        int ex = (int)((__float_as_uint(m2) >> 23) & 0xFF) - 127;
        float s = __uint_as_float((unsigned)(127 - ex) << 23);
        v = vn * s;
        Dacc += (double)ex + (double)Emat[b * 8 + c];
    }

    // ---- final LSE with T[:,STOP], max-subtracted (column is all NEG!) ----
    float cstop = Tm[n * TAGS + TSTOP];
    float mcl = (n < TAGS) ? cstop : -INFINITY;
    float mc = mcl;
    #pragma unroll
    for (int off = 32; off; off >>= 1) mc = fmaxf(mc, __shfl_xor(mc, off));
    float ts = (lane < 32 && n < TAGS) ? v * fexp2((cstop - mc) * LOG2E) : 0.f;
    #pragma unroll
    for (int off = 32; off; off >>= 1) ts += __shfl_xor(ts, off);
    double fwd = (Dacc + (double)flog2(ts)) * LN2d + (double)mc;

    // ---- gold path score (exact, from global feats) ----
    float g = 0.f;
    for (int l = lane; l < len; l += 64) {
        int tt = tags[(size_t)b * L + l];
        int pv = (l == 0) ? TSTART : tags[(size_t)b * L + l - 1];
        g += feats[((size_t)b * L + l) * TAGS + tt] + Tm[pv * TAGS + tt];
    }
    #pragma unroll
    for (int off = 32; off; off >>= 1) g += __shfl_xor(g, off);

    if (lane == 0) {
        double gold = (double)g + (double)Tm[tags[(size_t)b * L + len - 1] * TAGS + TSTOP];
        partial[b] = fwd - gold;
    }
}

// ==================== FALLBACK (round-2 serial kernel) ====================
__global__ __launch_bounds__(64)
void crf_fwd_kernel(const float* __restrict__ feats,
                    const float* __restrict__ Tm,
                    const int*   __restrict__ tags,
                    const int*   __restrict__ lengths,
                    double*      __restrict__ partial,
                    int B, int L)
{
    __shared__ float le[512 * TAGS];
    const int b    = blockIdx.x;
    const int lane = threadIdx.x;
    const int j    = (lane < TAGS) ? lane : 0;
    const float* fb  = feats + (size_t)b * L * TAGS;
    const int*   tg  = tags  + (size_t)b * L;
    const int    len = lengths[b];

    const int nv4 = (L * TAGS) >> 2;
    for (int it = lane; it < nv4; it += 64) {
        float4 v = reinterpret_cast<const float4*>(fb)[it];
        float4 e;
        e.x = fexp2(v.x * LOG2E); e.y = fexp2(v.y * LOG2E);
        e.z = fexp2(v.z * LOG2E); e.w = fexp2(v.w * LOG2E);
        reinterpret_cast<float4*>(le)[it] = e;
    }
    __syncthreads();

    float ET[TAGS];
    #pragma unroll
    for (int i = 0; i < TAGS; ++i) ET[i] = fexp2(Tm[i * TAGS + j] * LOG2E);

    float w0   = flog2(le[j]) + Tm[TSTART * TAGS + j] * LOG2E;
    float base = bcast(w0, 0);
    float P    = fexp2(w0 - base);
    float M2   = base;
    float Pa[TAGS];
    #pragma unroll
    for (int i = 0; i < TAGS; ++i) Pa[i] = bcast(P, i);
    const float* leb = le + j;

    auto STEP = [&](int l, float efv, float rsv, bool scaled) {
        float s0 = 0.f, s1 = 0.f, s2 = 0.f, s3 = 0.f;
        #pragma unroll
        for (int i = 0; i < TAGS; i += 4) {
            s0 = fmaf(ET[i + 0], Pa[i + 0], s0);
            s1 = fmaf(ET[i + 1], Pa[i + 1], s1);
            s2 = fmaf(ET[i + 2], Pa[i + 2], s2);
            s3 = fmaf(ET[i + 3], Pa[i + 3], s3);
        }
        float s   = (s0 + s1) + (s2 + s3);
        float cur = s * efv;
        float pn  = (l < len) ? cur : P;
        P = scaled ? pn * rsv : pn;
        #pragma unroll
        for (int i = 0; i < TAGS; ++i) Pa[i] = bcast(P, i);
    };

    float efb[4];
    #pragma unroll
    for (int k = 0; k < 4; ++k) { int ln = 1 + k; ln = (ln < L) ? ln : (L - 1); efb[k] = leb[ln * TAGS]; }

    float rs = 1.0f, lg0 = 0.0f;
    int l0 = 1;
    for (; l0 + 3 < L; l0 += 4) {
        if (l0 >= len) break;
        float efn[4];
        #pragma unroll
        for (int k = 0; k < 4; ++k) { int ln = l0 + 4 + k; ln = (ln < L) ? ln : (L - 1); efn[k] = leb[ln * TAGS]; }
        M2 += lg0;
        STEP(l0 + 0, efb[0], rs, true);
        STEP(l0 + 1, efb[1], 1.f, false);
        STEP(l0 + 2, efb[2], 1.f, false);
        STEP(l0 + 3, efb[3], 1.f, false);
        float p0 = Pa[0];
        rs = frcp(p0); lg0 = flog2(p0);
        #pragma unroll
        for (int k = 0; k < 4; ++k) efb[k] = efn[k];
    }
    if (l0 < len) {
        int rem = L - l0;
        M2 += lg0;
        if (rem > 0) STEP(l0 + 0, efb[0], rs, true);
        if (rem > 1) STEP(l0 + 1, efb[1], 1.f, false);
        if (rem > 2) STEP(l0 + 2, efb[2], 1.f, false);
        if (rem > 3) STEP(l0 + 3, efb[3], 1.f, false);
    }

    float cstop = Tm[j * TAGS + TSTOP];
    float mc = (lane < TAGS) ? cstop : -INFINITY;
    #pragma unroll
    for (int off = 32; off; off >>= 1) mc = fmaxf(mc, __shfl_xor(mc, off));
    float t = (lane < TAGS) ? P * fexp2((cstop - mc) * LOG2E) : 0.f;
    #pragma unroll
    for (int off = 32; off; off >>= 1) t += __shfl_xor(t, off);
    double fwd = ((double)M2 + (double)flog2(t)) * LN2d + (double)mc;

    float g = 0.f;
    for (int l = lane; l < len; l += 64) {
        int tt = tg[l];
        int pv = (l == 0) ? TSTART : tg[l - 1];
        g += flog2(le[l * TAGS + tt]) * LN2f + Tm[pv * TAGS + tt];
    }
    #pragma unroll
    for (int off = 32; off; off >>= 1) g += __shfl_xor(g, off);

    if (lane == 0) {
        double gold = (double)g + (double)Tm[tg[len - 1] * TAGS + TSTOP];
        partial[b] = fwd - gold;
    }
}

__global__ __launch_bounds__(256)
void crf_reduce_kernel(const double* __restrict__ partial, float* __restrict__ out, int B)
{
    __shared__ double sh[256];
    const int t = threadIdx.x;
    double acc = 0.0;
    for (int i = t; i < B; i += 256) acc += partial[i];
    sh[t] = acc;
    __syncthreads();
    for (int s = 128; s; s >>= 1) {
        if (t < s) sh[t] += sh[t + s];
        __syncthreads();
    }
    if (t == 0) out[0] = (float)sh[0];
}

extern "C" void kernel_launch(void* const* d_in, const int* in_sizes, int n_in,
                              void* d_out, int out_size, void* d_ws, size_t ws_size,
                              hipStream_t stream)
{
    const float* feats   = (const float*)d_in[0];
    const float* Tm      = (const float*)d_in[1];
    const int*   tags    = (const int*)d_in[2];
    const int*   lengths = (const int*)d_in[3];

    const int B = in_sizes[3];
    const int L = in_sizes[2] / B;

    size_t gbytes = (size_t)B * 8 * 1024 * sizeof(float);
    size_t ebytes = (size_t)B * 8 * sizeof(int);
    size_t need   = gbytes + ebytes + (size_t)B * sizeof(double);

    if (L == 512 && ws_size >= need) {
        float*  Gm      = (float*)d_ws;
        int*    Em      = (int*)((char*)d_ws + gbytes);
        double* partial = (double*)((char*)d_ws + gbytes + ebytes);
        crf_chunk_kernel<<<B * 8, 64, 0, stream>>>(feats, Tm, lengths, Gm, Em, L);
        crf_combine_kernel<<<B, 64, 0, stream>>>(feats, Tm, tags, lengths, Gm, Em, partial, L);
        crf_reduce_kernel<<<1, 256, 0, stream>>>(partial, (float*)d_out, B);
    } else {
        double* partial = (double*)d_ws;
        crf_fwd_kernel<<<B, 64, 0, stream>>>(feats, Tm, tags, lengths, partial, B, L);
        crf_reduce_kernel<<<1, 256, 0, stream>>>(partial, (float*)d_out, B);
    }
}

// Round 5
// 31.150 us; speedup vs baseline: 2.2267x; 1.2684x over previous
//
#include <hip/hip_runtime.h>
#include <hip/hip_bf16.h>
#include <math.h>

#define TAGS   20
#define TSTART (TAGS - 2)
#define TSTOP  (TAGS - 1)

constexpr float  LOG2E = 1.4426950408889634f;
constexpr float  LN2f  = 0.6931471805599453f;
constexpr double LN2d  = 0.69314718055994530942;

typedef __attribute__((ext_vector_type(8))) short short8;
typedef __attribute__((ext_vector_type(4))) float f32x4;
union U4 { unsigned int u[4]; short8 v; };

__device__ __forceinline__ unsigned int pk2(float lo, float hi) {
    float2 f2; f2.x = lo; f2.y = hi;
    __hip_bfloat162 h = __float22bfloat162_rn(f2);
    return *reinterpret_cast<unsigned int*>(&h);
}
// k-slot -> state-row permutation (split-half layout of gfx950 16x16x32),
// applied consistently to A and B; makes C/D per-lane regs == B per-lane
// k-slots (validated end-to-end in round 4: absmax 0.0).
__device__ __forceinline__ int rho(int k) {
    int g = k >> 3, i = k & 7;
    return (i < 4) ? (4 * g + i) : (16 + 4 * g + (i - 4));
}
__device__ __forceinline__ float fexp2(float x) { return exp2f(x); }
__device__ __forceinline__ float flog2(float x) { return log2f(x); }
__device__ __forceinline__ float frcp(float x) { return __builtin_amdgcn_rcpf(x); }
__device__ __forceinline__ float bcast(float v, int srclane) {
    return __int_as_float(__builtin_amdgcn_readlane(__float_as_int(v), srclane));
}

// ========================== FUSED KERNEL ==================================
// One block = one batch. 8 waves; wave w owns chunks w and w+8 (32 steps
// each, interleaved for ILP). Then a 4-level MFMA tree combines the 16
// chunk matrices in LDS (X side via LDS in A layout; Y side stays in the
// holder wave's accumulators). Final: v0^T * G_total, LSE, gold score.
__global__ __launch_bounds__(512)
void crf_fused_kernel(const float* __restrict__ feats,
                      const float* __restrict__ Tm,
                      const int*   __restrict__ tags,
                      const int*   __restrict__ lengths,
                      double*      __restrict__ partial,
                      int L)
{
    __shared__ float  smem[16 * 1024];   // 64 KB: ef staging; later tree slots (stride 1088)
    __shared__ float  sv[32];
    __shared__ int    EsX[8];
    __shared__ float  gred[8];
    __shared__ double fwd_sh;

    const int b    = blockIdx.x;
    const int tid  = threadIdx.x;
    const int w    = tid >> 6;
    const int lane = tid & 63;
    const int G    = lane >> 4, col = lane & 15;
    const int len  = lengths[b];

    // ---- stage ef = 2^(feat*log2e) for chunks w and w+8 (32x32, pads 0) ----
    #pragma unroll
    for (int s = 0; s < 2; ++s) {
        const int c = w + 8 * s;
        float* efc = smem + c * 1024;
        const float* fc = feats + ((size_t)b * L + (size_t)c * 32) * TAGS;
        for (int it = lane; it < 160; it += 64) {       // 160 float4 = 640 floats
            float4 v = reinterpret_cast<const float4*>(fc)[it];
            float vv[4] = {v.x, v.y, v.z, v.w};
            #pragma unroll
            for (int u = 0; u < 4; ++u) {
                int f = it * 4 + u;
                int t = f / TAGS, tag = f - t * TAGS;
                efc[t * 32 + tag] = fexp2(vv[u] * LOG2E);
            }
        }
        for (int q = lane; q < 32 * 12; q += 64) {
            int t = q / 12;
            efc[t * 32 + 20 + (q - t * 12)] = 0.f;
        }
    }
    __syncthreads();

    // ---- shared A fragments from T: A_x[m][k] = 2^(T[16x+m][rho(k)]*log2e) ----
    U4 A0, A1;
    #pragma unroll
    for (int t = 0; t < 4; ++t) {
        int k0 = 8 * G + 2 * t;
        int r0 = rho(k0), r1 = rho(k0 + 1);
        int m1 = 16 + col;
        float a00 = (r0 < TAGS) ? fexp2(Tm[col * TAGS + r0] * LOG2E) : 0.f;
        float a01 = (r1 < TAGS) ? fexp2(Tm[col * TAGS + r1] * LOG2E) : 0.f;
        float a10 = (m1 < TAGS && r0 < TAGS) ? fexp2(Tm[m1 * TAGS + r0] * LOG2E) : 0.f;
        float a11 = (m1 < TAGS && r1 < TAGS) ? fexp2(Tm[m1 * TAGS + r1] * LOG2E) : 0.f;
        A0.u[t] = pk2(a00, a01);
        A1.u[t] = pk2(a10, a11);
    }

    auto step = [&](f32x4& C00, f32x4& C01, f32x4& C10, f32x4& C11,
                    const float* efc, int t) {
        float4 e0 = *reinterpret_cast<const float4*>(&efc[t * 32 + 4 * G]);
        float4 e1 = *reinterpret_cast<const float4*>(&efc[t * 32 + 16 + 4 * G]);
        U4 B0, B1;
        B0.u[0] = pk2(C00[0] * e0.x, C00[1] * e0.y);
        B0.u[1] = pk2(C00[2] * e0.z, C00[3] * e0.w);
        B0.u[2] = pk2(C10[0] * e1.x, C10[1] * e1.y);
        B0.u[3] = pk2(C10[2] * e1.z, C10[3] * e1.w);
        B1.u[0] = pk2(C01[0] * e0.x, C01[1] * e0.y);
        B1.u[1] = pk2(C01[2] * e0.z, C01[3] * e0.w);
        B1.u[2] = pk2(C11[0] * e1.x, C11[1] * e1.y);
        B1.u[3] = pk2(C11[2] * e1.z, C11[3] * e1.w);
        f32x4 z = {0.f, 0.f, 0.f, 0.f};
        C00 = __builtin_amdgcn_mfma_f32_16x16x32_bf16(A0.v, B0.v, z, 0, 0, 0);
        C01 = __builtin_amdgcn_mfma_f32_16x16x32_bf16(A0.v, B1.v, z, 0, 0, 0);
        C10 = __builtin_amdgcn_mfma_f32_16x16x32_bf16(A1.v, B0.v, z, 0, 0, 0);
        C11 = __builtin_amdgcn_mfma_f32_16x16x32_bf16(A1.v, B1.v, z, 0, 0, 0);
    };
    auto strip = [&](f32x4& C00, f32x4& C01, f32x4& C10, f32x4& C11) -> int {
        float pr = C00[0] + C00[1] + C00[2] + C00[3] + C10[0] + C10[1] + C10[2] + C10[3];
        int pb = __builtin_amdgcn_readfirstlane(__float_as_int(pr));
        int ex = ((pb >> 23) & 0xFF) - 127;
        float s = __uint_as_float((unsigned)(127 - ex) << 23);
        #pragma unroll
        for (int j = 0; j < 4; ++j) { C00[j] *= s; C01[j] *= s; C10[j] *= s; C11[j] *= s; }
        return ex;
    };
    auto xwr = [&](int slot, const f32x4& C00, const f32x4& C01,
                   const f32x4& C10, const f32x4& C11, int E) {
        float* Xs = smem + slot * 1088;                 // row-major, stride 34
        #pragma unroll
        for (int j = 0; j < 4; ++j) {
            Xs[(4 * G + j) * 34 + col]           = C00[j];
            Xs[(4 * G + j) * 34 + col + 16]      = C01[j];
            Xs[(16 + 4 * G + j) * 34 + col]      = C10[j];
            Xs[(16 + 4 * G + j) * 34 + col + 16] = C11[j];
        }
        if (lane == 0) EsX[slot] = E;
    };
    auto prod = [&](int slot, f32x4& C00, f32x4& C01, f32x4& C10, f32x4& C11) -> int {
        const float* Xs = smem + slot * 1088;
        U4 Ax0, Ax1;
        #pragma unroll
        for (int t = 0; t < 4; ++t) {
            int r = rho(8 * G + 2 * t);                 // rho(k0), rho(k0+1) adjacent
            float2 x0 = *reinterpret_cast<const float2*>(&Xs[col * 34 + r]);
            float2 x1 = *reinterpret_cast<const float2*>(&Xs[(16 + col) * 34 + r]);
            Ax0.u[t] = pk2(x0.x, x0.y);
            Ax1.u[t] = pk2(x1.x, x1.y);
        }
        U4 B0, B1;
        B0.u[0] = pk2(C00[0], C00[1]);
        B0.u[1] = pk2(C00[2], C00[3]);
        B0.u[2] = pk2(C10[0], C10[1]);
        B0.u[3] = pk2(C10[2], C10[3]);
        B1.u[0] = pk2(C01[0], C01[1]);
        B1.u[1] = pk2(C01[2], C01[3]);
        B1.u[2] = pk2(C11[0], C11[1]);
        B1.u[3] = pk2(C11[2], C11[3]);
        f32x4 z = {0.f, 0.f, 0.f, 0.f};
        f32x4 n00 = __builtin_amdgcn_mfma_f32_16x16x32_bf16(Ax0.v, B0.v, z, 0, 0, 0);
        f32x4 n01 = __builtin_amdgcn_mfma_f32_16x16x32_bf16(Ax0.v, B1.v, z, 0, 0, 0);
        f32x4 n10 = __builtin_amdgcn_mfma_f32_16x16x32_bf16(Ax1.v, B0.v, z, 0, 0, 0);
        f32x4 n11 = __builtin_amdgcn_mfma_f32_16x16x32_bf16(Ax1.v, B1.v, z, 0, 0, 0);
        C00 = n00; C01 = n01; C10 = n10; C11 = n11;
        return strip(C00, C01, C10, C11);
    };

    // ---- two interleaved 32-step chunk products (sets A=chunk w, B=chunk w+8) ----
    f32x4 aC00, aC01, aC10, aC11, bC00, bC01, bC10, bC11;
    #pragma unroll
    for (int j = 0; j < 4; ++j) {
        float d = (4 * G + j == col) ? 1.f : 0.f;
        aC00[j] = d; aC11[j] = d; aC01[j] = 0.f; aC10[j] = 0.f;
        bC00[j] = d; bC11[j] = d; bC01[j] = 0.f; bC10[j] = 0.f;
    }
    int aE = 0, bE = 0;

    const int cB  = w + 8;
    const int loA = (w == 0) ? 1 : w * 32;
    const int hiA = min(w * 32 + 31, len - 1);
    const int loB = cB * 32;
    const int hiB = min(cB * 32 + 31, len - 1);
    int nA = hiA - loA + 1; if (nA < 0) nA = 0;
    int nB = hiB - loB + 1; if (nB < 0) nB = 0;
    const int n = max(nA, nB);
    const float* efA = smem + w * 1024;
    const float* efB = smem + cB * 1024;

    int lA = hiA, lB = hiB;
    for (int i = 0; i < n; ++i) {
        if (i < nA) { step(aC00, aC01, aC10, aC11, efA, lA - w * 32);  --lA; }
        if (i < nB) { step(bC00, bC01, bC10, bC11, efB, lB - cB * 32); --lB; }
        if ((i & 3) == 3) {
            aE += strip(aC00, aC01, aC10, aC11);
            bE += strip(bC00, bC01, bC10, bC11);
        }
    }
    __syncthreads();   // ef region dead; reuse smem as tree slots

    // ---- tree level 1: P_p = G_{2p} * G_{2p+1} ----
    if ((w & 1) == 0) {
        xwr(w / 2,     aC00, aC01, aC10, aC11, aE);
        xwr(w / 2 + 4, bC00, bC01, bC10, bC11, bE);
    }
    __syncthreads();
    if (w & 1) {
        int pA = (w - 1) / 2;
        aE += EsX[pA]     + prod(pA,     aC00, aC01, aC10, aC11);
        bE += EsX[pA + 4] + prod(pA + 4, bC00, bC01, bC10, bC11);
    }
    __syncthreads();
    // ---- level 2: Q_q = P_{2q} * P_{2q+1} ----
    if (w == 1 || w == 5) {
        xwr((w - 1) / 4,     aC00, aC01, aC10, aC11, aE);
        xwr((w - 1) / 4 + 2, bC00, bC01, bC10, bC11, bE);
    }
    __syncthreads();
    if (w == 3 || w == 7) {
        int q = (w - 3) / 4;
        aE += EsX[q]     + prod(q,     aC00, aC01, aC10, aC11);
        bE += EsX[q + 2] + prod(q + 2, bC00, bC01, bC10, bC11);
    }
    __syncthreads();
    // ---- level 3: R_r = Q_{2r} * Q_{2r+1} ----
    if (w == 3) {
        xwr(0, aC00, aC01, aC10, aC11, aE);
        xwr(1, bC00, bC01, bC10, bC11, bE);
    }
    __syncthreads();
    if (w == 7) {
        aE += EsX[0] + prod(0, aC00, aC01, aC10, aC11);
        bE += EsX[1] + prod(1, bC00, bC01, bC10, bC11);
    }
    __syncthreads();
    // ---- level 4 (same wave: no barrier needed between write & read) ----
    if (w == 7) {
        xwr(0, aC00, aC01, aC10, aC11, aE);
        int ex = prod(0, bC00, bC01, bC10, bC11);    // G_total = R_0 * R_1
        int fE = aE + bE + ex;
        float* Gt = smem;                             // col-major: Gt[n*34 + r]
        #pragma unroll
        for (int j = 0; j < 4; ++j) {
            Gt[col * 34 + 4 * G + j]            = bC00[j];
            Gt[col * 34 + 16 + 4 * G + j]       = bC10[j];
            Gt[(col + 16) * 34 + 4 * G + j]     = bC01[j];
            Gt[(col + 16) * 34 + 16 + 4 * G + j]= bC11[j];
        }
        if (lane == 0) EsX[0] = fE;
    }
    __syncthreads();

    // ---- final: part^T = v0^T G_total ; LSE with T[:,STOP] (max-subtracted) ----
    if (w == 0) {
        const int n2 = lane & 31;
        float p = (n2 < TAGS) ? (feats[(size_t)b * L * TAGS + n2] + Tm[TSTART * TAGS + n2]) * LOG2E
                              : -1e30f;
        float mx = p;
        #pragma unroll
        for (int off = 32; off; off >>= 1) mx = fmaxf(mx, __shfl_xor(mx, off));
        float v = (n2 < TAGS) ? fexp2(p - mx) : 0.f;
        if (lane < 32) sv[lane] = v;                  // same-wave DS ordering
        const float* Gt = smem;
        float vn = 0.f;
        #pragma unroll
        for (int r = 0; r < 32; r += 2) {
            float2 g2 = *reinterpret_cast<const float2*>(&Gt[n2 * 34 + r]);
            vn = fmaf(sv[r], g2.x, vn);
            vn = fmaf(sv[r + 1], g2.y, vn);
        }
        float cstop = Tm[n2 * TAGS + TSTOP];
        float mc = (n2 < TAGS) ? cstop : -INFINITY;
        #pragma unroll
        for (int off = 32; off; off >>= 1) mc = fmaxf(mc, __shfl_xor(mc, off));
        float ts = (lane < 32 && n2 < TAGS) ? vn * fexp2((cstop - mc) * LOG2E) : 0.f;
        #pragma unroll
        for (int off = 32; off; off >>= 1) ts += __shfl_xor(ts, off);
        if (lane == 0)
            fwd_sh = ((double)mx + (double)EsX[0] + (double)flog2(ts)) * LN2d + (double)mc;
    }

    // ---- gold path score (all 512 threads) ----
    float g = 0.f;
    for (int l = tid; l < len; l += 512) {
        int tt = tags[(size_t)b * L + l];
        int pv = (l == 0) ? TSTART : tags[(size_t)b * L + l - 1];
        g += feats[((size_t)b * L + l) * TAGS + tt] + Tm[pv * TAGS + tt];
    }
    #pragma unroll
    for (int off = 32; off; off >>= 1) g += __shfl_xor(g, off);
    if (lane == 0) gred[w] = g;
    __syncthreads();

    if (tid == 0) {
        float gs = gred[0] + gred[1] + gred[2] + gred[3]
                 + gred[4] + gred[5] + gred[6] + gred[7];
        double gold = (double)gs + (double)Tm[tags[(size_t)b * L + len - 1] * TAGS + TSTOP];
        partial[b] = fwd_sh - gold;
    }
}

// ==================== FALLBACK (round-2 serial kernel) ====================
__global__ __launch_bounds__(64)
void crf_fwd_kernel(const float* __restrict__ feats,
                    const float* __restrict__ Tm,
                    const int*   __restrict__ tags,
                    const int*   __restrict__ lengths,
                    double*      __restrict__ partial,
                    int B, int L)
{
    __shared__ float le[512 * TAGS];
    const int b    = blockIdx.x;
    const int lane = threadIdx.x;
    const int j    = (lane < TAGS) ? lane : 0;
    const float* fb  = feats + (size_t)b * L * TAGS;
    const int*   tg  = tags  + (size_t)b * L;
    const int    len = lengths[b];

    const int nv4 = (L * TAGS) >> 2;
    for (int it = lane; it < nv4; it += 64) {
        float4 v = reinterpret_cast<const float4*>(fb)[it];
        float4 e;
        e.x = fexp2(v.x * LOG2E); e.y = fexp2(v.y * LOG2E);
        e.z = fexp2(v.z * LOG2E); e.w = fexp2(v.w * LOG2E);
        reinterpret_cast<float4*>(le)[it] = e;
    }
    __syncthreads();

    float ET[TAGS];
    #pragma unroll
    for (int i = 0; i < TAGS; ++i) ET[i] = fexp2(Tm[i * TAGS + j] * LOG2E);

    float w0   = flog2(le[j]) + Tm[TSTART * TAGS + j] * LOG2E;
    float base = bcast(w0, 0);
    float P    = fexp2(w0 - base);
    float M2   = base;
    float Pa[TAGS];
    #pragma unroll
    for (int i = 0; i < TAGS; ++i) Pa[i] = bcast(P, i);
    const float* leb = le + j;

    auto STEP = [&](int l, float efv, float rsv, bool scaled) {
        float s0 = 0.f, s1 = 0.f, s2 = 0.f, s3 = 0.f;
        #pragma unroll
        for (int i = 0; i < TAGS; i += 4) {
            s0 = fmaf(ET[i + 0], Pa[i + 0], s0);
            s1 = fmaf(ET[i + 1], Pa[i + 1], s1);
            s2 = fmaf(ET[i + 2], Pa[i + 2], s2);
            s3 = fmaf(ET[i + 3], Pa[i + 3], s3);
        }
        float s   = (s0 + s1) + (s2 + s3);
        float cur = s * efv;
        float pn  = (l < len) ? cur : P;
        P = scaled ? pn * rsv : pn;
        #pragma unroll
        for (int i = 0; i < TAGS; ++i) Pa[i] = bcast(P, i);
    };

    float efb[4];
    #pragma unroll
    for (int k = 0; k < 4; ++k) { int ln = 1 + k; ln = (ln < L) ? ln : (L - 1); efb[k] = leb[ln * TAGS]; }

    float rs = 1.0f, lg0 = 0.0f;
    int l0 = 1;
    for (; l0 + 3 < L; l0 += 4) {
        if (l0 >= len) break;
        float efn[4];
        #pragma unroll
        for (int k = 0; k < 4; ++k) { int ln = l0 + 4 + k; ln = (ln < L) ? ln : (L - 1); efn[k] = leb[ln * TAGS]; }
        M2 += lg0;
        STEP(l0 + 0, efb[0], rs, true);
        STEP(l0 + 1, efb[1], 1.f, false);
        STEP(l0 + 2, efb[2], 1.f, false);
        STEP(l0 + 3, efb[3], 1.f, false);
        float p0 = Pa[0];
        rs = frcp(p0); lg0 = flog2(p0);
        #pragma unroll
        for (int k = 0; k < 4; ++k) efb[k] = efn[k];
    }
    if (l0 < len) {
        int rem = L - l0;
        M2 += lg0;
        if (rem > 0) STEP(l0 + 0, efb[0], rs, true);
        if (rem > 1) STEP(l0 + 1, efb[1], 1.f, false);
        if (rem > 2) STEP(l0 + 2, efb[2], 1.f, false);
        if (rem > 3) STEP(l0 + 3, efb[3], 1.f, false);
    }

    float cstop = Tm[j * TAGS + TSTOP];
    float mc = (lane < TAGS) ? cstop : -INFINITY;
    #pragma unroll
    for (int off = 32; off; off >>= 1) mc = fmaxf(mc, __shfl_xor(mc, off));
    float t = (lane < TAGS) ? P * fexp2((cstop - mc) * LOG2E) : 0.f;
    #pragma unroll
    for (int off = 32; off; off >>= 1) t += __shfl_xor(t, off);
    double fwd = ((double)M2 + (double)flog2(t)) * LN2d + (double)mc;

    float g = 0.f;
    for (int l = lane; l < len; l += 64) {
        int tt = tg[l];
        int pv = (l == 0) ? TSTART : tg[l - 1];
        g += flog2(le[l * TAGS + tt]) * LN2f + Tm[pv * TAGS + tt];
    }
    #pragma unroll
    for (int off = 32; off; off >>= 1) g += __shfl_xor(g, off);

    if (lane == 0) {
        double gold = (double)g + (double)Tm[tg[len - 1] * TAGS + TSTOP];
        partial[b] = fwd - gold;
    }
}

__global__ __launch_bounds__(256)
void crf_reduce_kernel(const double* __restrict__ partial, float* __restrict__ out, int B)
{
    __shared__ double sh[256];
    const int t = threadIdx.x;
    double acc = 0.0;
    for (int i = t; i < B; i += 256) acc += partial[i];
    sh[t] = acc;
    __syncthreads();
    for (int s = 128; s; s >>= 1) {
        if (t < s) sh[t] += sh[t + s];
        __syncthreads();
    }
    if (t == 0) out[0] = (float)sh[0];
}

extern "C" void kernel_launch(void* const* d_in, const int* in_sizes, int n_in,
                              void* d_out, int out_size, void* d_ws, size_t ws_size,
                              hipStream_t stream)
{
    const float* feats   = (const float*)d_in[0];
    const float* Tm      = (const float*)d_in[1];
    const int*   tags    = (const int*)d_in[2];
    const int*   lengths = (const int*)d_in[3];

    const int B = in_sizes[3];
    const int L = in_sizes[2] / B;

    double* partial = (double*)d_ws;

    if (L == 512 && ws_size >= (size_t)B * sizeof(double)) {
        crf_fused_kernel<<<B, 512, 0, stream>>>(feats, Tm, tags, lengths, partial, L);
        crf_reduce_kernel<<<1, 256, 0, stream>>>(partial, (float*)d_out, B);
    } else {
        crf_fwd_kernel<<<B, 64, 0, stream>>>(feats, Tm, tags, lengths, partial, B, L);
        crf_reduce_kernel<<<1, 256, 0, stream>>>(partial, (float*)d_out, B);
    }
}

// Round 7
// 28.870 us; speedup vs baseline: 2.4025x; 1.0790x over previous
//
#include <hip/hip_runtime.h>
#include <hip/hip_bf16.h>
#include <math.h>

#define TAGS   20
#define TSTART (TAGS - 2)
#define TSTOP  (TAGS - 1)

constexpr float  LOG2E = 1.4426950408889634f;
constexpr float  LN2f  = 0.6931471805599453f;
constexpr double LN2d  = 0.69314718055994530942;

typedef __attribute__((ext_vector_type(8))) short short8;
typedef __attribute__((ext_vector_type(4))) float f32x4;
union U4 { unsigned int u[4]; short8 v; };

// f32x2 -> packed bf16x2, round-half-up: +0x8000 on the raw bits then take
// the high halves via one v_perm_b32 (selector 0x07060302 — the standard
// composable_kernel idiom). 3 VALU ops total vs ~11 for the hip_bf16
// software-RNE path (round 5's hidden per-step tax). All inputs on this
// path are >= 0 and strip-renormalized, so the carry can't reach inf.
__device__ __forceinline__ unsigned int pk2(float lo, float hi) {
    unsigned int a = __float_as_uint(hi) + 0x8000u;
    unsigned int b = __float_as_uint(lo) + 0x8000u;
#if __has_builtin(__builtin_amdgcn_perm)
    return __builtin_amdgcn_perm(a, b, 0x07060302u);   // {a[31:16], b[31:16]}
#else
    return (a & 0xFFFF0000u) | (b >> 16);
#endif
}
__device__ __forceinline__ float fexp2(float x) { return exp2f(x); }
__device__ __forceinline__ float flog2(float x) { return log2f(x); }
__device__ __forceinline__ float frcp(float x) { return __builtin_amdgcn_rcpf(x); }
__device__ __forceinline__ float bcast(float v, int srclane) {
    return __int_as_float(__builtin_amdgcn_readlane(__float_as_int(v), srclane));
}
// k-slot -> state-row permutation (split-half layout of gfx950 16x16x32),
// applied consistently to A and B; makes C/D per-lane regs == B per-lane
// k-slots (validated end-to-end: rounds 4/5 absmax 0.0).
__device__ __forceinline__ int rho(int k) {
    int g = k >> 3, i = k & 7;
    return (i < 4) ? (4 * g + i) : (16 + 4 * g + (i - 4));
}

// ========================== FUSED KERNEL ==================================
// One block = one batch. 8 waves; wave w owns chunks w and w+8 (32 steps
// each, interleaved for ILP). Then a 4-level MFMA tree combines the 16
// chunk matrices in LDS. Final: v0^T * G_total, LSE, gold score.
__global__ __launch_bounds__(512)
void crf_fused_kernel(const float* __restrict__ feats,
                      const float* __restrict__ Tm,
                      const int*   __restrict__ tags,
                      const int*   __restrict__ lengths,
                      double*      __restrict__ partial,
                      int L)
{
    __shared__ float  smem[16 * 1024];   // 64 KB: ef staging; later tree slots (stride 1088)
    __shared__ float  sv[32];
    __shared__ int    EsX[8];
    __shared__ float  gred[8];
    __shared__ double fwd_sh;

    const int b    = blockIdx.x;
    const int tid  = threadIdx.x;
    const int w    = tid >> 6;
    const int lane = tid & 63;
    const int G    = lane >> 4, col = lane & 15;
    const int len  = lengths[b];

    // ---- stage ef = 2^(feat*log2e) for chunks w and w+8 (32x32, pads 0) ----
    #pragma unroll
    for (int s = 0; s < 2; ++s) {
        const int c = w + 8 * s;
        float* efc = smem + c * 1024;
        const float* fc = feats + ((size_t)b * L + (size_t)c * 32) * TAGS;
        for (int it = lane; it < 160; it += 64) {       // 160 float4 = 640 floats
            float4 v = reinterpret_cast<const float4*>(fc)[it];
            float vv[4] = {v.x, v.y, v.z, v.w};
            #pragma unroll
            for (int u = 0; u < 4; ++u) {
                int f = it * 4 + u;
                int t = f / TAGS, tag = f - t * TAGS;
                efc[t * 32 + tag] = fexp2(vv[u] * LOG2E);
            }
        }
        for (int q = lane; q < 32 * 12; q += 64) {
            int t = q / 12;
            efc[t * 32 + 20 + (q - t * 12)] = 0.f;
        }
    }
    __syncthreads();

    // ---- shared A fragments from T: A_x[m][k] = 2^(T[16x+m][rho(k)]*log2e) ----
    U4 A0, A1;
    #pragma unroll
    for (int t = 0; t < 4; ++t) {
        int k0 = 8 * G + 2 * t;
        int r0 = rho(k0), r1 = rho(k0 + 1);
        int m1 = 16 + col;
        float a00 = (r0 < TAGS) ? fexp2(Tm[col * TAGS + r0] * LOG2E) : 0.f;
        float a01 = (r1 < TAGS) ? fexp2(Tm[col * TAGS + r1] * LOG2E) : 0.f;
        float a10 = (m1 < TAGS && r0 < TAGS) ? fexp2(Tm[m1 * TAGS + r0] * LOG2E) : 0.f;
        float a11 = (m1 < TAGS && r1 < TAGS) ? fexp2(Tm[m1 * TAGS + r1] * LOG2E) : 0.f;
        A0.u[t] = pk2(a00, a01);
        A1.u[t] = pk2(a10, a11);
    }

    auto step = [&](f32x4& C00, f32x4& C01, f32x4& C10, f32x4& C11,
                    const float* efc, int t) {
        float4 e0 = *reinterpret_cast<const float4*>(&efc[t * 32 + 4 * G]);
        float4 e1 = *reinterpret_cast<const float4*>(&efc[t * 32 + 16 + 4 * G]);
        U4 B0, B1;
        B0.u[0] = pk2(C00[0] * e0.x, C00[1] * e0.y);
        B0.u[1] = pk2(C00[2] * e0.z, C00[3] * e0.w);
        B0.u[2] = pk2(C10[0] * e1.x, C10[1] * e1.y);
        B0.u[3] = pk2(C10[2] * e1.z, C10[3] * e1.w);
        B1.u[0] = pk2(C01[0] * e0.x, C01[1] * e0.y);
        B1.u[1] = pk2(C01[2] * e0.z, C01[3] * e0.w);
        B1.u[2] = pk2(C11[0] * e1.x, C11[1] * e1.y);
        B1.u[3] = pk2(C11[2] * e1.z, C11[3] * e1.w);
        f32x4 z = {0.f, 0.f, 0.f, 0.f};
        C00 = __builtin_amdgcn_mfma_f32_16x16x32_bf16(A0.v, B0.v, z, 0, 0, 0);
        C01 = __builtin_amdgcn_mfma_f32_16x16x32_bf16(A0.v, B1.v, z, 0, 0, 0);
        C10 = __builtin_amdgcn_mfma_f32_16x16x32_bf16(A1.v, B0.v, z, 0, 0, 0);
        C11 = __builtin_amdgcn_mfma_f32_16x16x32_bf16(A1.v, B1.v, z, 0, 0, 0);
    };
    auto strip = [&](f32x4& C00, f32x4& C01, f32x4& C10, f32x4& C11) -> int {
        float pr = C00[0] + C00[1] + C00[2] + C00[3] + C10[0] + C10[1] + C10[2] + C10[3];
        int pb = __builtin_amdgcn_readfirstlane(__float_as_int(pr));
        int ex = ((pb >> 23) & 0xFF) - 127;
        float s = __uint_as_float((unsigned)(127 - ex) << 23);
        #pragma unroll
        for (int j = 0; j < 4; ++j) { C00[j] *= s; C01[j] *= s; C10[j] *= s; C11[j] *= s; }
        return ex;
    };
    auto xwr = [&](int slot, const f32x4& C00, const f32x4& C01,
                   const f32x4& C10, const f32x4& C11, int E) {
        float* Xs = smem + slot * 1088;                 // row-major, stride 34
        #pragma unroll
        for (int j = 0; j < 4; ++j) {
            Xs[(4 * G + j) * 34 + col]           = C00[j];
            Xs[(4 * G + j) * 34 + col + 16]      = C01[j];
            Xs[(16 + 4 * G + j) * 34 + col]      = C10[j];
            Xs[(16 + 4 * G + j) * 34 + col + 16] = C11[j];
        }
        if (lane == 0) EsX[slot] = E;
    };
    auto prod = [&](int slot, f32x4& C00, f32x4& C01, f32x4& C10, f32x4& C11) -> int {
        const float* Xs = smem + slot * 1088;
        U4 Ax0, Ax1;
        #pragma unroll
        for (int t = 0; t < 4; ++t) {
            int r = rho(8 * G + 2 * t);                 // rho(k0), rho(k0+1) adjacent
            float2 x0 = *reinterpret_cast<const float2*>(&Xs[col * 34 + r]);
            float2 x1 = *reinterpret_cast<const float2*>(&Xs[(16 + col) * 34 + r]);
            Ax0.u[t] = pk2(x0.x, x0.y);
            Ax1.u[t] = pk2(x1.x, x1.y);
        }
        U4 B0, B1;
        B0.u[0] = pk2(C00[0], C00[1]);
        B0.u[1] = pk2(C00[2], C00[3]);
        B0.u[2] = pk2(C10[0], C10[1]);
        B0.u[3] = pk2(C10[2], C10[3]);
        B1.u[0] = pk2(C01[0], C01[1]);
        B1.u[1] = pk2(C01[2], C01[3]);
        B1.u[2] = pk2(C11[0], C11[1]);
        B1.u[3] = pk2(C11[2], C11[3]);
        f32x4 z = {0.f, 0.f, 0.f, 0.f};
        f32x4 n00 = __builtin_amdgcn_mfma_f32_16x16x32_bf16(Ax0.v, B0.v, z, 0, 0, 0);
        f32x4 n01 = __builtin_amdgcn_mfma_f32_16x16x32_bf16(Ax0.v, B1.v, z, 0, 0, 0);
        f32x4 n10 = __builtin_amdgcn_mfma_f32_16x16x32_bf16(Ax1.v, B0.v, z, 0, 0, 0);
        f32x4 n11 = __builtin_amdgcn_mfma_f32_16x16x32_bf16(Ax1.v, B1.v, z, 0, 0, 0);
        C00 = n00; C01 = n01; C10 = n10; C11 = n11;
        return strip(C00, C01, C10, C11);
    };

    // ---- two interleaved 32-step chunk products (chains: chunk w, chunk w+8) ----
    f32x4 aC00, aC01, aC10, aC11, bC00, bC01, bC10, bC11;
    #pragma unroll
    for (int j = 0; j < 4; ++j) {
        float d = (4 * G + j == col) ? 1.f : 0.f;
        aC00[j] = d; aC11[j] = d; aC01[j] = 0.f; aC10[j] = 0.f;
        bC00[j] = d; bC11[j] = d; bC01[j] = 0.f; bC10[j] = 0.f;
    }
    int aE = 0, bE = 0;

    const int cB  = w + 8;
    const int loA = (w == 0) ? 1 : w * 32;
    const int hiA = min(w * 32 + 31, len - 1);
    const int loB = cB * 32;
    const int hiB = min(cB * 32 + 31, len - 1);
    int nA = hiA - loA + 1; if (nA < 0) nA = 0;
    int nB = hiB - loB + 1; if (nB < 0) nB = 0;
    const int n = max(nA, nB);
    const float* efA = smem + w * 1024;
    const float* efB = smem + cB * 1024;

    int lA = hiA, lB = hiB;
    for (int i = 0; i < n; ++i) {
        if (i < nA) { step(aC00, aC01, aC10, aC11, efA, lA - w * 32);  --lA; }
        if (i < nB) { step(bC00, bC01, bC10, bC11, efB, lB - cB * 32); --lB; }
        if ((i & 3) == 3) {
            aE += strip(aC00, aC01, aC10, aC11);
            bE += strip(bC00, bC01, bC10, bC11);
        }
    }
    __syncthreads();   // ef region dead; reuse smem as tree slots

    // ---- tree level 1: P_p = G_{2p} * G_{2p+1} ----
    if ((w & 1) == 0) {
        xwr(w / 2,     aC00, aC01, aC10, aC11, aE);
        xwr(w / 2 + 4, bC00, bC01, bC10, bC11, bE);
    }
    __syncthreads();
    if (w & 1) {
        int pA = (w - 1) / 2;
        aE += EsX[pA]     + prod(pA,     aC00, aC01, aC10, aC11);
        bE += EsX[pA + 4] + prod(pA + 4, bC00, bC01, bC10, bC11);
    }
    __syncthreads();
    // ---- level 2: Q_q = P_{2q} * P_{2q+1} ----
    if (w == 1 || w == 5) {
        xwr((w - 1) / 4,     aC00, aC01, aC10, aC11, aE);
        xwr((w - 1) / 4 + 2, bC00, bC01, bC10, bC11, bE);
    }
    __syncthreads();
    if (w == 3 || w == 7) {
        int q = (w - 3) / 4;
        aE += EsX[q]     + prod(q,     aC00, aC01, aC10, aC11);
        bE += EsX[q + 2] + prod(q + 2, bC00, bC01, bC10, bC11);
    }
    __syncthreads();
    // ---- level 3: R_r = Q_{2r} * Q_{2r+1} ----
    if (w == 3) {
        xwr(0, aC00, aC01, aC10, aC11, aE);
        xwr(1, bC00, bC01, bC10, bC11, bE);
    }
    __syncthreads();
    if (w == 7) {
        aE += EsX[0] + prod(0, aC00, aC01, aC10, aC11);
        bE += EsX[1] + prod(1, bC00, bC01, bC10, bC11);
    }
    __syncthreads();
    // ---- level 4 (same wave: no barrier needed between write & read) ----
    if (w == 7) {
        xwr(0, aC00, aC01, aC10, aC11, aE);
        int ex = prod(0, bC00, bC01, bC10, bC11);    // G_total = R_0 * R_1
        int fE = aE + bE + ex;
        float* Gt = smem;                             // col-major: Gt[n*34 + r]
        #pragma unroll
        for (int j = 0; j < 4; ++j) {
            Gt[col * 34 + 4 * G + j]            = bC00[j];
            Gt[col * 34 + 16 + 4 * G + j]       = bC10[j];
            Gt[(col + 16) * 34 + 4 * G + j]     = bC01[j];
            Gt[(col + 16) * 34 + 16 + 4 * G + j]= bC11[j];
        }
        if (lane == 0) EsX[0] = fE;
    }
    __syncthreads();

    // ---- final: part^T = v0^T G_total ; LSE with T[:,STOP] (max-subtracted) ----
    if (w == 0) {
        const int n2 = lane & 31;
        float p = (n2 < TAGS) ? (feats[(size_t)b * L * TAGS + n2] + Tm[TSTART * TAGS + n2]) * LOG2E
                              : -1e30f;
        float mx = p;
        #pragma unroll
        for (int off = 32; off; off >>= 1) mx = fmaxf(mx, __shfl_xor(mx, off));
        float v = (n2 < TAGS) ? fexp2(p - mx) : 0.f;
        if (lane < 32) sv[lane] = v;                  // same-wave DS ordering
        const float* Gt = smem;
        float vn = 0.f;
        #pragma unroll
        for (int r = 0; r < 32; r += 2) {
            float2 g2 = *reinterpret_cast<const float2*>(&Gt[n2 * 34 + r]);
            vn = fmaf(sv[r], g2.x, vn);
            vn = fmaf(sv[r + 1], g2.y, vn);
        }
        float cstop = Tm[n2 * TAGS + TSTOP];
        float mc = (n2 < TAGS) ? cstop : -INFINITY;
        #pragma unroll
        for (int off = 32; off; off >>= 1) mc = fmaxf(mc, __shfl_xor(mc, off));
        float ts = (lane < 32 && n2 < TAGS) ? vn * fexp2((cstop - mc) * LOG2E) : 0.f;
        #pragma unroll
        for (int off = 32; off; off >>= 1) ts += __shfl_xor(ts, off);
        if (lane == 0)
            fwd_sh = ((double)mx + (double)EsX[0] + (double)flog2(ts)) * LN2d + (double)mc;
    }

    // ---- gold path score (all 512 threads) ----
    float g = 0.f;
    for (int l = tid; l < len; l += 512) {
        int tt = tags[(size_t)b * L + l];
        int pv = (l == 0) ? TSTART : tags[(size_t)b * L + l - 1];
        g += feats[((size_t)b * L + l) * TAGS + tt] + Tm[pv * TAGS + tt];
    }
    #pragma unroll
    for (int off = 32; off; off >>= 1) g += __shfl_xor(g, off);
    if (lane == 0) gred[w] = g;
    __syncthreads();

    if (tid == 0) {
        float gs = gred[0] + gred[1] + gred[2] + gred[3]
                 + gred[4] + gred[5] + gred[6] + gred[7];
        double gold = (double)gs + (double)Tm[tags[(size_t)b * L + len - 1] * TAGS + TSTOP];
        partial[b] = fwd_sh - gold;
    }
}

// ==================== FALLBACK (round-2 serial kernel) ====================
__global__ __launch_bounds__(64)
void crf_fwd_kernel(const float* __restrict__ feats,
                    const float* __restrict__ Tm,
                    const int*   __restrict__ tags,
                    const int*   __restrict__ lengths,
                    double*      __restrict__ partial,
                    int B, int L)
{
    __shared__ float le[512 * TAGS];
    const int b    = blockIdx.x;
    const int lane = threadIdx.x;
    const int j    = (lane < TAGS) ? lane : 0;
    const float* fb  = feats + (size_t)b * L * TAGS;
    const int*   tg  = tags  + (size_t)b * L;
    const int    len = lengths[b];

    const int nv4 = (L * TAGS) >> 2;
    for (int it = lane; it < nv4; it += 64) {
        float4 v = reinterpret_cast<const float4*>(fb)[it];
        float4 e;
        e.x = fexp2(v.x * LOG2E); e.y = fexp2(v.y * LOG2E);
        e.z = fexp2(v.z * LOG2E); e.w = fexp2(v.w * LOG2E);
        reinterpret_cast<float4*>(le)[it] = e;
    }
    __syncthreads();

    float ET[TAGS];
    #pragma unroll
    for (int i = 0; i < TAGS; ++i) ET[i] = fexp2(Tm[i * TAGS + j] * LOG2E);

    float w0   = flog2(le[j]) + Tm[TSTART * TAGS + j] * LOG2E;
    float base = bcast(w0, 0);
    float P    = fexp2(w0 - base);
    float M2   = base;
    float Pa[TAGS];
    #pragma unroll
    for (int i = 0; i < TAGS; ++i) Pa[i] = bcast(P, i);
    const float* leb = le + j;

    auto STEP = [&](int l, float efv, float rsv, bool scaled) {
        float s0 = 0.f, s1 = 0.f, s2 = 0.f, s3 = 0.f;
        #pragma unroll
        for (int i = 0; i < TAGS; i += 4) {
            s0 = fmaf(ET[i + 0], Pa[i + 0], s0);
            s1 = fmaf(ET[i + 1], Pa[i + 1], s1);
            s2 = fmaf(ET[i + 2], Pa[i + 2], s2);
            s3 = fmaf(ET[i + 3], Pa[i + 3], s3);
        }
        float s   = (s0 + s1) + (s2 + s3);
        float cur = s * efv;
        float pn  = (l < len) ? cur : P;
        P = scaled ? pn * rsv : pn;
        #pragma unroll
        for (int i = 0; i < TAGS; ++i) Pa[i] = bcast(P, i);
    };

    float efb[4];
    #pragma unroll
    for (int k = 0; k < 4; ++k) { int ln = 1 + k; ln = (ln < L) ? ln : (L - 1); efb[k] = leb[ln * TAGS]; }

    float rs = 1.0f, lg0 = 0.0f;
    int l0 = 1;
    for (; l0 + 3 < L; l0 += 4) {
        if (l0 >= len) break;
        float efn[4];
        #pragma unroll
        for (int k = 0; k < 4; ++k) { int ln = l0 + 4 + k; ln = (ln < L) ? ln : (L - 1); efn[k] = leb[ln * TAGS]; }
        M2 += lg0;
        STEP(l0 + 0, efb[0], rs, true);
        STEP(l0 + 1, efb[1], 1.f, false);
        STEP(l0 + 2, efb[2], 1.f, false);
        STEP(l0 + 3, efb[3], 1.f, false);
        float p0 = Pa[0];
        rs = frcp(p0); lg0 = flog2(p0);
        #pragma unroll
        for (int k = 0; k < 4; ++k) efb[k] = efn[k];
    }
    if (l0 < len) {
        int rem = L - l0;
        M2 += lg0;
        if (rem > 0) STEP(l0 + 0, efb[0], rs, true);
        if (rem > 1) STEP(l0 + 1, efb[1], 1.f, false);
        if (rem > 2) STEP(l0 + 2, efb[2], 1.f, false);
        if (rem > 3) STEP(l0 + 3, efb[3], 1.f, false);
    }

    float cstop = Tm[j * TAGS + TSTOP];
    float mc = (lane < TAGS) ? cstop : -INFINITY;
    #pragma unroll
    for (int off = 32; off; off >>= 1) mc = fmaxf(mc, __shfl_xor(mc, off));
    float t = (lane < TAGS) ? P * fexp2((cstop - mc) * LOG2E) : 0.f;
    #pragma unroll
    for (int off = 32; off; off >>= 1) t += __shfl_xor(t, off);
    double fwd = ((double)M2 + (double)flog2(t)) * LN2d + (double)mc;

    float g = 0.f;
    for (int l = lane; l < len; l += 64) {
        int tt = tg[l];
        int pv = (l == 0) ? TSTART : tg[l - 1];
        g += flog2(le[l * TAGS + tt]) * LN2f + Tm[pv * TAGS + tt];
    }
    #pragma unroll
    for (int off = 32; off; off >>= 1) g += __shfl_xor(g, off);

    if (lane == 0) {
        double gold = (double)g + (double)Tm[tg[len - 1] * TAGS + TSTOP];
        partial[b] = fwd - gold;
    }
}

__global__ __launch_bounds__(256)
void crf_reduce_kernel(const double* __restrict__ partial, float* __restrict__ out, int B)
{
    __shared__ double sh[256];
    const int t = threadIdx.x;
    double acc = 0.0;
    for (int i = t; i < B; i += 256) acc += partial[i];
    sh[t] = acc;
    __syncthreads();
    for (int s = 128; s; s >>= 1) {
        if (t < s) sh[t] += sh[t + s];
        __syncthreads();
    }
    if (t == 0) out[0] = (float)sh[0];
}

extern "C" void kernel_launch(void* const* d_in, const int* in_sizes, int n_in,
                              void* d_out, int out_size, void* d_ws, size_t ws_size,
                              hipStream_t stream)
{
    const float* feats   = (const float*)d_in[0];
    const float* Tm      = (const float*)d_in[1];
    const int*   tags    = (const int*)d_in[2];
    const int*   lengths = (const int*)d_in[3];

    const int B = in_sizes[3];
    const int L = in_sizes[2] / B;

    double* partial = (double*)d_ws;

    if (L == 512 && ws_size >= (size_t)B * sizeof(double)) {
        crf_fused_kernel<<<B, 512, 0, stream>>>(feats, Tm, tags, lengths, partial, L);
        crf_reduce_kernel<<<1, 256, 0, stream>>>(partial, (float*)d_out, B);
    } else {
        crf_fwd_kernel<<<B, 64, 0, stream>>>(feats, Tm, tags, lengths, partial, B, L);
        crf_reduce_kernel<<<1, 256, 0, stream>>>(partial, (float*)d_out, B);
    }
}